// Round 8
// baseline (156.857 us; speedup 1.0000x reference)
//
#include <hip/hip_runtime.h>
#include <math.h>

#define TS   32
#define NPIX 1024
#define DF   72      // real feature dim
#define KP   96      // padded K: 3 MFMA k-steps of 32
#define IMH  320
#define IMW  320
#define NTW  10
#define NTILE 100
#define STRIPS 8     // 8 partial blocks per tile

// ws layout: Fhi at 0, Sq at SQ_OFF (proven), partials at 64 MiB
#define F_UNITS_PER_TILE 12288           // 64 rt * 3 ks * 4 c * 16 rows
#define FHI_BYTES (NTILE * F_UNITS_PER_TILE * 16)   // 19,660,800
#define SQ_OFF    (2 * FHI_BYTES)                   // 39,321,600
#define PART_OFF  (64u << 20)                       // 67,108,864 (+13.1MB)

#define K2LOG2E 2.0813689810056077f      // (log2 e)^2: exp(-sqrt(x)) = exp2(-sqrt(K2*x))
#define FSCALE  2.0402789f               // sqrt(2*K2LOG2E): Gram = 2*K2*<F,F>

typedef __attribute__((ext_vector_type(8))) short bf16x8;   // MFMA A/B frag
typedef __attribute__((ext_vector_type(8))) unsigned short u16x8;
typedef __attribute__((ext_vector_type(4))) float f32x4;    // MFMA C/D
typedef __attribute__((ext_vector_type(4))) __fp16 f16x4;   // 16x16x16 f16 A/B frag
typedef __attribute__((ext_vector_type(2))) __fp16 f16x2;

// ---------------- kernel A: feature build (RNE bf16, pre-scaled) + sqf ----
__global__ __launch_bounds__(256)
void nlm_feat_kernel(const float* __restrict__ img,
                     u16x8* __restrict__ Fhi, float* __restrict__ Sq)
{
    __shared__ float Ploc[3][6][36];
    __shared__ int   ofsl[KP];
    const int tid  = threadIdx.x;
    const int part = blockIdx.x;    // 0..15
    const int tile = blockIdx.y;
    const int by   = (tile / NTW) * TS;
    const int bx   = (tile % NTW) * TS;
    const float* Pf = &Ploc[0][0][0];

    for (int idx = tid; idx < 3 * 6 * 36; idx += 256) {
        int c   = idx / 216;
        int rem = idx - c * 216;
        int yl  = rem / 36;
        int x   = rem - yl * 36;
        int y   = 2 * part + yl;
        int iy  = min(max(y - 2, 0), TS - 1);
        int ix  = min(max(x - 2, 0), TS - 1);
        Ploc[c][yl][x] = img[(c * IMH + by + iy) * IMW + bx + ix];
    }
    if (tid < KP) {
        int k = tid, v = 0;
        if (k < DF) {
            int c = k / 24, o = k - c * 24;
            int kk = o + (o >= 12);
            int i = kk / 5, j = kk - (kk / 5) * 5;
            v = c * 216 + i * 36 + j;
        }
        ofsl[k] = v;
    }
    __syncthreads();

    if (tid < 64) {
        int m  = part * 64 + tid;
        int my = m >> 5, mx = m & 31;
        int ly0 = my - 2 * part;
        float s = 0.f;
        #pragma unroll
        for (int k = 0; k < 25; ++k) {
            if (k == 12) continue;
            int i = k / 5, j = k - (k / 5) * 5;
            float v0 = Ploc[0][ly0 + i][mx + j];
            float v1 = Ploc[1][ly0 + i][mx + j];
            float v2 = Ploc[2][ly0 + i][mx + j];
            s = fmaf(v0, v0, s); s = fmaf(v1, v1, s); s = fmaf(v2, v2, s);
        }
        Sq[tile * NPIX + m] = s * K2LOG2E;   // K2 * |F|^2
    }

    #pragma unroll
    for (int q = 0; q < 3; ++q) {
        int u    = part * 768 + q * 256 + tid;
        int row  = u & 15;
        int c4   = (u >> 4) & 3;
        int rks  = u >> 6;
        int ks   = rks - (rks / 3) * 3;
        int rt   = rks / 3;
        int r    = rt * 16 + row;
        int lbase = ((r >> 5) - 2 * part) * 36 + (r & 31);
        u16x8 h;
        #pragma unroll
        for (int j = 0; j < 8; ++j) {
            int k = ks * 32 + c4 * 8 + j;
            unsigned short hs = 0;
            if (k < DF) {
                float f = Pf[lbase + ofsl[k]] * FSCALE;
                unsigned int uu = __float_as_uint(f);
                hs = (unsigned short)((uu + 0x7fffu + ((uu >> 16) & 1u)) >> 16);
            }
            h[j] = hs;
        }
        Fhi[tile * F_UNITS_PER_TILE + u] = h;
    }
}

// ---------------- kernel B: balanced symmetric Gram + dual-side PV --------
// R18 (fix of R17's stall): every VMEM load unconditional (clamped prefetch
// index, diag as pre-step, pair-unrolled inner loop) so counted vmcnt
// pipelining survives; mirror-pair (i, 63-i) waves -> 65 frags/wave uniform.
__global__ __launch_bounds__(256)
__attribute__((amdgpu_waves_per_eu(4, 8)))
void nlm_sym_kernel(const float* __restrict__ img,
                    const bf16x8* __restrict__ Fhi,
                    const float* __restrict__ SqK,
                    float* __restrict__ part)
{
    __shared__ __fp16 Yhi[4][1032];
    __shared__ __fp16 Ylo[4][1032];
    __shared__ float acc[NPIX][4];      // 16 KB block accumulator

    // XCD-pinned: grid 832 = 8 XCD * 104; XCD x owns tiles {x, x+8, ...}
    const int x   = blockIdx.x & 7;
    const int idx0 = blockIdx.x >> 3;       // 0..103
    const int m0  = idx0 >> 3;              // 0..12
    const int bb  = idx0 & 7;               // block-in-tile 0..7
    const int tile = x + 8 * m0;
    if (tile >= NTILE) return;              // whole block exits (before syncs)

    const int tid  = threadIdx.x;
    const int lane = tid & 63;
    const int wv   = tid >> 6;              // 0..3
    const int quad = lane >> 4;
    const int col  = lane & 15;
    const int ycol = col & 3;
    const int iw0  = bb * 4 + wv;           // pair index 0..31
    const int by   = (tile / NTW) * TS;
    const int bx   = (tile % NTW) * TS;

    const bf16x8* FHt = Fhi + tile * F_UNITS_PER_TILE;
    const float*  Sqt = SqK + tile * NPIX;

    for (int idx = tid; idx < 1024; idx += 256)
        *(f32x4*)&acc[idx][0] = (f32x4){0.f, 0.f, 0.f, 0.f};

    // stage Y = [y0,y1,y2,1] as f16 hi + lo residual
    for (int idx = tid; idx < 1024; idx += 256) {
        int c = idx >> 8, m4 = (idx & 255) << 2;
        f32x4 v = {1.f, 1.f, 1.f, 1.f};
        if (c < 3) v = *(const f32x4*)&img[(c * IMH + by + (m4 >> 5)) * IMW + bx + (m4 & 31)];
        f16x4 h, l;
        #pragma unroll
        for (int j = 0; j < 4; ++j) {
            h[j] = (__fp16)v[j];
            l[j] = (__fp16)(v[j] - (float)h[j]);
        }
        *(f16x4*)&Yhi[c][m4] = h;
        *(f16x4*)&Ylo[c][m4] = l;
    }

    bf16x8 sgn;
    #pragma unroll
    for (int j = 0; j < 8; ++j) sgn[j] = (short)0x8000;
    f16x4 idf;
    #pragma unroll
    for (int j = 0; j < 4; ++j)
        idf[j] = (__fp16)((quad * 4 + j == col) ? 1.f : 0.f);

    __syncthreads();

    bf16x8 aA0, aA1, aA2, aB0, aB1, aB2;
    f32x4 sqA, sqB;
    f16x4 bhA, blA, bhB, blB;

#define LOADJ(j_, a0, a1, a2, sq, bh, bl)                        \
    do {                                                         \
        int _j = (j_);                                           \
        a0 = FHt[(_j * 3 + 0) * 64 + lane];                      \
        a1 = FHt[(_j * 3 + 1) * 64 + lane];                      \
        a2 = FHt[(_j * 3 + 2) * 64 + lane];                      \
        sq = *(const f32x4*)&Sqt[_j * 16 + quad * 4];            \
        bh = *(const f16x4*)&Yhi[ycol][_j * 16 + quad * 4];      \
        bl = *(const f16x4*)&Ylo[ycol][_j * 16 + quad * 4];      \
    } while (0)

// off-diagonal fragment: n-side into Dn (regs), m-side via transpose-MFMA
// + LDS atomic scatter. No conditional VMEM anywhere.
#define COMPUTEJ(j_, a0, a1, a2, sq, bh, bl)                                         \
    do {                                                                             \
        int _j = (j_);                                                               \
        f32x4 C = {sq[0] + sni, sq[1] + sni, sq[2] + sni, sq[3] + sni};              \
        C = __builtin_amdgcn_mfma_f32_16x16x32_bf16(a0, bN0, C, 0, 0, 0);            \
        C = __builtin_amdgcn_mfma_f32_16x16x32_bf16(a1, bN1, C, 0, 0, 0);            \
        C = __builtin_amdgcn_mfma_f32_16x16x32_bf16(a2, bN2, C, 0, 0, 0);            \
        float d[4];                                                                  \
        _Pragma("unroll")                                                            \
        for (int i = 0; i < 4; ++i) {                                                \
            float s2 = fmaxf(C[i], 0.f);                                             \
            d[i] = __builtin_amdgcn_exp2f(-__builtin_amdgcn_sqrtf(s2));              \
        }                                                                            \
        f16x2 p0 = __builtin_amdgcn_cvt_pkrtz(d[0], d[1]);                           \
        f16x2 p1 = __builtin_amdgcn_cvt_pkrtz(d[2], d[3]);                           \
        f16x4 wp = __builtin_shufflevector(p0, p1, 0, 1, 2, 3);                      \
        Dn = __builtin_amdgcn_mfma_f32_16x16x16f16(wp, bh, Dn, 0, 0, 0);             \
        Dn = __builtin_amdgcn_mfma_f32_16x16x16f16(wp, bl, Dn, 0, 0, 0);             \
        f32x4 Z = {0.f, 0.f, 0.f, 0.f};                                              \
        f32x4 T = __builtin_amdgcn_mfma_f32_16x16x16f16(wp, idf, Z, 0, 0, 0);        \
        f16x2 q0 = __builtin_amdgcn_cvt_pkrtz(T[0], T[1]);                           \
        f16x2 q1 = __builtin_amdgcn_cvt_pkrtz(T[2], T[3]);                           \
        f16x4 wq = __builtin_shufflevector(q0, q1, 0, 1, 2, 3);                      \
        f32x4 D2 = __builtin_amdgcn_mfma_f32_16x16x16f16(wq, bhN, Z, 0, 0, 0);       \
        D2 = __builtin_amdgcn_mfma_f32_16x16x16f16(wq, blN, D2, 0, 0, 0);            \
        if (col < 4) {                                                               \
            atomicAdd(&acc[_j * 16 + quad * 4 + 0][col], D2[0]);                     \
            atomicAdd(&acc[_j * 16 + quad * 4 + 1][col], D2[1]);                     \
            atomicAdd(&acc[_j * 16 + quad * 4 + 2][col], D2[2]);                     \
            atomicAdd(&acc[_j * 16 + quad * 4 + 3][col], D2[3]);                     \
        }                                                                            \
    } while (0)

// diagonal fragment: n-side only, self-weight zeroed
#define COMPUTED(a0, a1, a2, sq, bh, bl)                                             \
    do {                                                                             \
        f32x4 C = {sq[0] + sni, sq[1] + sni, sq[2] + sni, sq[3] + sni};              \
        C = __builtin_amdgcn_mfma_f32_16x16x32_bf16(a0, bN0, C, 0, 0, 0);            \
        C = __builtin_amdgcn_mfma_f32_16x16x32_bf16(a1, bN1, C, 0, 0, 0);            \
        C = __builtin_amdgcn_mfma_f32_16x16x32_bf16(a2, bN2, C, 0, 0, 0);            \
        float d[4];                                                                  \
        _Pragma("unroll")                                                            \
        for (int i = 0; i < 4; ++i) {                                                \
            float s2 = fmaxf(C[i], 0.f);                                             \
            d[i] = __builtin_amdgcn_exp2f(-__builtin_amdgcn_sqrtf(s2));              \
            if (quad * 4 + i == col) d[i] = 0.f;                                     \
        }                                                                            \
        f16x2 p0 = __builtin_amdgcn_cvt_pkrtz(d[0], d[1]);                           \
        f16x2 p1 = __builtin_amdgcn_cvt_pkrtz(d[2], d[3]);                           \
        f16x4 wp = __builtin_shufflevector(p0, p1, 0, 1, 2, 3);                      \
        Dn = __builtin_amdgcn_mfma_f32_16x16x16f16(wp, bh, Dn, 0, 0, 0);             \
        Dn = __builtin_amdgcn_mfma_f32_16x16x16f16(wp, bl, Dn, 0, 0, 0);             \
    } while (0)

    #pragma unroll 2
    for (int ph = 0; ph < 2; ++ph) {
        const int ic  = ph ? (63 - iw0) : iw0;
        const int cnt = 63 - ic;            // 32..63 (ph0) / 0..31 (ph1)

        // pinned i-side operands (unconditional loads, once per phase)
        bf16x8 bN0 = FHt[(ic * 3 + 0) * 64 + lane] ^ sgn;
        bf16x8 bN1 = FHt[(ic * 3 + 1) * 64 + lane] ^ sgn;
        bf16x8 bN2 = FHt[(ic * 3 + 2) * 64 + lane] ^ sgn;
        const float sni = Sqt[ic * 16 + col];
        const f16x4 bhN = *(const f16x4*)&Yhi[ycol][ic * 16 + quad * 4];
        const f16x4 blN = *(const f16x4*)&Ylo[ycol][ic * 16 + quad * 4];
        f32x4 Dn = {0.f, 0.f, 0.f, 0.f};

        // diagonal pre-step
        LOADJ(ic, aA0, aA1, aA2, sqA, bhA, blA);
        COMPUTED(aA0, aA1, aA2, sqA, bhA, blA);

        // branch-free pair-unrolled pipeline; prefetch index clamped to 63
        int jn = ic + 1;
        LOADJ(jn < 63 ? jn : 63, aA0, aA1, aA2, sqA, bhA, blA);
        for (int n = 0; n + 1 < cnt; n += 2) {
            LOADJ(jn + 1, aB0, aB1, aB2, sqB, bhB, blB);
            COMPUTEJ(jn, aA0, aA1, aA2, sqA, bhA, blA);
            LOADJ(jn + 2 < 63 ? jn + 2 : 63, aA0, aA1, aA2, sqA, bhA, blA);
            COMPUTEJ(jn + 1, aB0, aB1, aB2, sqB, bhB, blB);
            jn += 2;
        }
        if (cnt & 1)
            COMPUTEJ(jn, aA0, aA1, aA2, sqA, bhA, blA);

        // flush n-side rows (i-tile) into the block accumulator
        if (col < 4) {
            #pragma unroll
            for (int s = 0; s < 4; ++s)
                atomicAdd(&acc[ic * 16 + quad * 4 + s][col], Dn[s]);
        }
    }
#undef LOADJ
#undef COMPUTEJ
#undef COMPUTED

    __syncthreads();   // all scatters visible

    float* P = part + (size_t)(tile * STRIPS + bb) * (NPIX * 4);
    for (int idx = tid; idx < 1024; idx += 256)
        *(f32x4*)&P[idx * 4] = *(const f32x4*)&acc[idx][0];
}

// ---------------- kernel C: partial reduce + normalize --------------------
__global__ __launch_bounds__(256)
void nlm_reduce_kernel(const float* __restrict__ part, float* __restrict__ out)
{
    const int bid  = blockIdx.x;            // 0..399
    const int tile = bid >> 2;
    const int p    = ((bid & 3) << 8) + threadIdx.x;   // pixel 0..1023
    const float* base = part + (size_t)tile * (STRIPS * NPIX * 4) + p * 4;
    float s0 = 0.f, s1 = 0.f, s2 = 0.f, s3 = 0.f;
    #pragma unroll
    for (int st = 0; st < STRIPS; ++st) {
        f32x4 v = *(const f32x4*)(base + st * (NPIX * 4));
        s0 += v[0]; s1 += v[1]; s2 += v[2]; s3 += v[3];
    }
    float inv = 1.f / s3;                   // ones-channel = rowsum
    int by = (tile / NTW) * TS, bx = (tile % NTW) * TS;
    int gy = by + (p >> 5), gx = bx + (p & 31);
    out[(0 * IMH + gy) * IMW + gx] = s0 * inv;
    out[(1 * IMH + gy) * IMW + gx] = s1 * inv;
    out[(2 * IMH + gy) * IMW + gx] = s2 * inv;
}

extern "C" void kernel_launch(void* const* d_in, const int* in_sizes, int n_in,
                              void* d_out, int out_size, void* d_ws, size_t ws_size,
                              hipStream_t stream) {
    const float* img = (const float*)d_in[0];
    float* out = (float*)d_out;
    char* ws = (char*)d_ws;
    u16x8* Fhi = (u16x8*)ws;
    float* Sq  = (float*)(ws + SQ_OFF);
    float* prt = (float*)(ws + PART_OFF);

    dim3 fgrid(16, NTILE);
    nlm_feat_kernel<<<fgrid, 256, 0, stream>>>(img, Fhi, Sq);
    nlm_sym_kernel<<<dim3(832), 256, 0, stream>>>(img, (const bf16x8*)Fhi, Sq, prt);
    nlm_reduce_kernel<<<dim3(400), 256, 0, stream>>>(prt, out);
}

// Round 9
// 114.514 us; speedup vs baseline: 1.3698x; 1.3698x over previous
//
#include <hip/hip_runtime.h>
#include <math.h>

#define TS   32
#define PT   36
#define NPIX 1024
#define DF   72      // real feature dim
#define KP   96      // padded K: 3 MFMA k-steps of 32
#define IMH  320
#define IMW  320
#define NTW  10
#define NTILE 100

// ws layout offsets unchanged from proven R3..R11
#define F_UNITS_PER_TILE 12288           // 64 rt * 3 ks * 4 c * 16 rows
#define FHI_BYTES (NTILE * F_UNITS_PER_TILE * 16)   // 19,660,800
#define SQ_OFF    (2 * FHI_BYTES)                   // 39,321,600

#define K2LOG2E 2.0813689810056077f      // (log2 e)^2: exp(-sqrt(x)) = exp2(-sqrt(K2*x))
#define FSCALE  2.0402789f               // sqrt(2*K2LOG2E): Gram = 2*K2*<F,F>

typedef __attribute__((ext_vector_type(8))) short bf16x8;   // MFMA A/B frag
typedef __attribute__((ext_vector_type(8))) unsigned short u16x8;
typedef __attribute__((ext_vector_type(4))) float f32x4;    // MFMA C/D
typedef __attribute__((ext_vector_type(4))) __fp16 f16x4;   // 16x16x16 f16 A/B frag
typedef __attribute__((ext_vector_type(2))) __fp16 f16x2;

// ---------------- kernel A: feature build (RNE bf16, pre-scaled) + sqf ----
// Features scaled by FSCALE so the Gram MFMA directly yields 2*K2*<Fm,Fn>;
// Sq = K2*|F|^2. (Verified bit-identical absmax across R6-R8.)
__global__ __launch_bounds__(256)
void nlm_feat_kernel(const float* __restrict__ img,
                     u16x8* __restrict__ Fhi, float* __restrict__ Sq)
{
    __shared__ float Ploc[3][6][36];   // padded rows [2p, 2p+6) of the tile
    __shared__ int   ofsl[KP];
    const int tid  = threadIdx.x;
    const int part = blockIdx.x;    // 0..15
    const int tile = blockIdx.y;
    const int by   = (tile / NTW) * TS;
    const int bx   = (tile % NTW) * TS;
    const float* Pf = &Ploc[0][0][0];

    for (int idx = tid; idx < 3 * 6 * 36; idx += 256) {
        int c   = idx / 216;
        int rem = idx - c * 216;
        int yl  = rem / 36;
        int x   = rem - yl * 36;
        int y   = 2 * part + yl;
        int iy  = min(max(y - 2, 0), TS - 1);
        int ix  = min(max(x - 2, 0), TS - 1);
        Ploc[c][yl][x] = img[(c * IMH + by + iy) * IMW + bx + ix];
    }
    if (tid < KP) {
        int k = tid, v = 0;
        if (k < DF) {
            int c = k / 24, o = k - c * 24;
            int kk = o + (o >= 12);
            int i = kk / 5, j = kk - (kk / 5) * 5;
            v = c * 216 + i * 36 + j;
        }
        ofsl[k] = v;
    }
    __syncthreads();

    if (tid < 64) {
        int m  = part * 64 + tid;
        int my = m >> 5, mx = m & 31;
        int ly0 = my - 2 * part;
        float s = 0.f;
        #pragma unroll
        for (int k = 0; k < 25; ++k) {
            if (k == 12) continue;
            int i = k / 5, j = k - (k / 5) * 5;
            float v0 = Ploc[0][ly0 + i][mx + j];
            float v1 = Ploc[1][ly0 + i][mx + j];
            float v2 = Ploc[2][ly0 + i][mx + j];
            s = fmaf(v0, v0, s); s = fmaf(v1, v1, s); s = fmaf(v2, v2, s);
        }
        Sq[tile * NPIX + m] = s * K2LOG2E;   // K2 * |F|^2
    }

    #pragma unroll
    for (int q = 0; q < 3; ++q) {
        int u    = part * 768 + q * 256 + tid;
        int row  = u & 15;
        int c4   = (u >> 4) & 3;
        int rks  = u >> 6;
        int ks   = rks - (rks / 3) * 3;
        int rt   = rks / 3;
        int r    = rt * 16 + row;
        int lbase = ((r >> 5) - 2 * part) * 36 + (r & 31);
        u16x8 h;
        #pragma unroll
        for (int j = 0; j < 8; ++j) {
            int k = ks * 32 + c4 * 8 + j;
            unsigned short hs = 0;
            if (k < DF) {
                float f = Pf[lbase + ofsl[k]] * FSCALE;
                unsigned int uu = __float_as_uint(f);
                hs = (unsigned short)((uu + 0x7fffu + ((uu >> 16) & 1u)) >> 16);
            }
            h[j] = hs;
        }
        Fhi[tile * F_UNITS_PER_TILE + u] = h;
    }
}

// ---------------- kernel B: Gram MFMA + PV-MFMA (R4 structure + C-init) ---
// R12: operand-swapped Gram; densities feed K=16 f16 PV MFMA in-layout.
// R13: XCD-swizzled 1-D grid (FETCH 84->10.8MB).
// R14: 2-deep register pipeline, 256-thread blocks (best measured: R4).
// R19: C-init algebra (from R6, the only verified-safe piece of R6-R8):
//      acc init = sqm[i]+snK[t], bN negated once -> C_out = s2 directly;
//      removes 8 fma + constant mul per iteration. R15 512-thr (+5.3),
//      R16 LDS table (+14), R17/R18 symmetric triangle (+38/+50) all
//      regressed and are reverted.
__global__ __launch_bounds__(256)
__attribute__((amdgpu_waves_per_eu(4, 8)))
void nlm_gemm_kernel(const float* __restrict__ img,
                     const bf16x8* __restrict__ Fhi,
                     const float* __restrict__ SqK, float* __restrict__ out)
{
    __shared__ __fp16 Yhi[4][1032];   // pitch 1032: banks 0/4/8/12 across c
    __shared__ __fp16 Ylo[4][1032];
    __shared__ float red[4][2][16][4];  // [wave][t][row][c]

    const int tid  = threadIdx.x;
    const int lane = tid & 63;
    const int wv   = tid >> 6;
    // XCD swizzle: block i -> XCD i%8; each XCD gets a contiguous work slab.
    const int i0   = blockIdx.x;
    const int w    = (i0 & 7) * 400 + (i0 >> 3);
    const int tile = w >> 5;
    const int rtA  = (w & 31) * 2;
    const int by   = (tile / NTW) * TS;
    const int bx   = (tile % NTW) * TS;
    const int quad = lane >> 4;
    const int col  = lane & 15;
    const int ycol = col & 3;           // cols 4..15 dup; D cols 4..15 unused

    const bf16x8* FHt = Fhi + tile * F_UNITS_PER_TILE;
    const float*  Sqt = SqK + tile * NPIX;

    // stage Y = [y0,y1,y2,1] as f16 hi + f16 residual, float4-vectorized
    for (int idx = tid; idx < 1024; idx += 256) {
        int c = idx >> 8, m4 = (idx & 255) << 2;
        f32x4 v = {1.f, 1.f, 1.f, 1.f};
        if (c < 3) v = *(const f32x4*)&img[(c * IMH + by + (m4 >> 5)) * IMW + bx + (m4 & 31)];
        f16x4 h, l;
        #pragma unroll
        for (int j = 0; j < 4; ++j) {
            h[j] = (__fp16)v[j];
            l[j] = (__fp16)(v[j] - (float)h[j]);
        }
        *(f16x4*)&Yhi[c][m4] = h;
        *(f16x4*)&Ylo[c][m4] = l;
    }

    // block's n-features, pinned, negated (Gram C = init - 2K2<Fm,Fn>)
    bf16x8 bN[2][3];
    bf16x8 sgn;
    #pragma unroll
    for (int j = 0; j < 8; ++j) sgn[j] = (short)0x8000;
    #pragma unroll
    for (int t = 0; t < 2; ++t)
        #pragma unroll
        for (int ks = 0; ks < 3; ++ks)
            bN[t][ks] = FHt[((rtA + t) * 3 + ks) * 64 + lane] ^ sgn;
    asm volatile(""
        : "+v"(bN[0][0]), "+v"(bN[0][1]), "+v"(bN[0][2]),
          "+v"(bN[1][0]), "+v"(bN[1][1]), "+v"(bN[1][2]));

    float snK[2];
    #pragma unroll
    for (int t = 0; t < 2; ++t)
        snK[t] = Sqt[(rtA + t) * 16 + col];

    f32x4 DpvH0 = {0.f, 0.f, 0.f, 0.f};
    f32x4 DpvL0 = {0.f, 0.f, 0.f, 0.f};
    f32x4 DpvH1 = {0.f, 0.f, 0.f, 0.f};
    f32x4 DpvL1 = {0.f, 0.f, 0.f, 0.f};

    __syncthreads();

    const int mtBase = wv * 16;

    // two-deep ping-pong pipeline: named buffer sets A/B (no runtime indexing)
    bf16x8 aFA0, aFA1, aFA2, aFB0, aFB1, aFB2;
    f32x4 sqA, sqB;
    f16x4 bhiA, bloA, bhiB, bloB;

#define LOADF(mt, a0, a1, a2, sq, bh, bl)                      \
    do {                                                       \
        int _mt = (mt);                                        \
        a0 = FHt[(_mt * 3 + 0) * 64 + lane];                   \
        a1 = FHt[(_mt * 3 + 1) * 64 + lane];                   \
        a2 = FHt[(_mt * 3 + 2) * 64 + lane];                   \
        sq = *(const f32x4*)&Sqt[_mt * 16 + quad * 4];         \
        bh = *(const f16x4*)&Yhi[ycol][_mt * 16 + quad * 4];   \
        bl = *(const f16x4*)&Ylo[ycol][_mt * 16 + quad * 4];   \
    } while (0)

#define COMPUTE(mt, a0, a1, a2, sq, bh, bl)                                          \
    do {                                                                             \
        int _mt = (mt);                                                              \
        f32x4 C0 = {sq[0] + snK[0], sq[1] + snK[0], sq[2] + snK[0], sq[3] + snK[0]}; \
        f32x4 C1 = {sq[0] + snK[1], sq[1] + snK[1], sq[2] + snK[1], sq[3] + snK[1]}; \
        C0 = __builtin_amdgcn_mfma_f32_16x16x32_bf16(a0, bN[0][0], C0, 0, 0, 0);     \
        C1 = __builtin_amdgcn_mfma_f32_16x16x32_bf16(a0, bN[1][0], C1, 0, 0, 0);     \
        C0 = __builtin_amdgcn_mfma_f32_16x16x32_bf16(a1, bN[0][1], C0, 0, 0, 0);     \
        C1 = __builtin_amdgcn_mfma_f32_16x16x32_bf16(a1, bN[1][1], C1, 0, 0, 0);     \
        C0 = __builtin_amdgcn_mfma_f32_16x16x32_bf16(a2, bN[0][2], C0, 0, 0, 0);     \
        C1 = __builtin_amdgcn_mfma_f32_16x16x32_bf16(a2, bN[1][2], C1, 0, 0, 0);     \
        _Pragma("unroll")                                                            \
        for (int t = 0; t < 2; ++t) {                                                \
            f32x4 C = t ? C1 : C0;                                                   \
            float d[4];                                                              \
            _Pragma("unroll")                                                        \
            for (int i = 0; i < 4; ++i) {                                            \
                float s2 = fmaxf(C[i], 0.f);                                         \
                d[i] = __builtin_amdgcn_exp2f(-__builtin_amdgcn_sqrtf(s2));          \
            }                                                                        \
            if (_mt == rtA + t) {                                                    \
                _Pragma("unroll")                                                    \
                for (int i = 0; i < 4; ++i)                                          \
                    if (quad * 4 + i == col) d[i] = 0.f;                             \
            }                                                                        \
            f16x2 p0 = __builtin_amdgcn_cvt_pkrtz(d[0], d[1]);                       \
            f16x2 p1 = __builtin_amdgcn_cvt_pkrtz(d[2], d[3]);                       \
            f16x4 wp = __builtin_shufflevector(p0, p1, 0, 1, 2, 3);                  \
            if (t == 0) {                                                            \
                DpvH0 = __builtin_amdgcn_mfma_f32_16x16x16f16(wp, bh, DpvH0, 0, 0, 0); \
                DpvL0 = __builtin_amdgcn_mfma_f32_16x16x16f16(wp, bl, DpvL0, 0, 0, 0); \
            } else {                                                                 \
                DpvH1 = __builtin_amdgcn_mfma_f32_16x16x16f16(wp, bh, DpvH1, 0, 0, 0); \
                DpvL1 = __builtin_amdgcn_mfma_f32_16x16x16f16(wp, bl, DpvL1, 0, 0, 0); \
            }                                                                        \
        }                                                                            \
    } while (0)

    LOADF(mtBase, aFA0, aFA1, aFA2, sqA, bhiA, bloA);
    #pragma unroll
    for (int it2 = 0; it2 < 8; ++it2) {
        const int mt0 = mtBase + it2 * 2;
        LOADF(mt0 + 1, aFB0, aFB1, aFB2, sqB, bhiB, bloB);
        COMPUTE(mt0, aFA0, aFA1, aFA2, sqA, bhiA, bloA);
        if (it2 < 7)
            LOADF(mt0 + 2, aFA0, aFA1, aFA2, sqA, bhiA, bloA);
        COMPUTE(mt0 + 1, aFB0, aFB1, aFB2, sqB, bhiB, bloB);
    }
#undef LOADF
#undef COMPUTE

    // cross-wave reduce: Dpv row = n-local (4q+i), col = channel (0..3 valid)
    if (col < 4) {
        #pragma unroll
        for (int i = 0; i < 4; ++i) {
            red[wv][0][quad * 4 + i][col] = DpvH0[i] + DpvL0[i];
            red[wv][1][quad * 4 + i][col] = DpvH1[i] + DpvL1[i];
        }
    }
    __syncthreads();

    if (tid < 128) {
        int n = tid >> 2, c = tid & 3;
        int t = n >> 4, r = n & 15;
        float s = red[0][t][r][c] + red[1][t][r][c]
                + red[2][t][r][c] + red[3][t][r][c];
        float rs = __shfl(s, (tid & 63) | 3, 64);   // c==3 slot = rowsum
        if (c < 3) {
            int nn = rtA * 16 + n;
            int gy = by + (nn >> 5), gx = bx + (nn & 31);
            out[(c * IMH + gy) * IMW + gx] = s * (1.0f / rs);
        }
    }
}

extern "C" void kernel_launch(void* const* d_in, const int* in_sizes, int n_in,
                              void* d_out, int out_size, void* d_ws, size_t ws_size,
                              hipStream_t stream) {
    const float* img = (const float*)d_in[0];
    float* out = (float*)d_out;
    char* ws = (char*)d_ws;
    u16x8* Fhi = (u16x8*)ws;
    float* Sq  = (float*)(ws + SQ_OFF);

    dim3 fgrid(16, NTILE);
    nlm_feat_kernel<<<fgrid, 256, 0, stream>>>(img, Fhi, Sq);
    nlm_gemm_kernel<<<dim3(3200), 256, 0, stream>>>(img, (const bf16x8*)Fhi, Sq, out);
}

// Round 10
// 111.197 us; speedup vs baseline: 1.4106x; 1.0298x over previous
//
#include <hip/hip_runtime.h>
#include <math.h>

#define TS   32
#define PT   36
#define NPIX 1024
#define DF   72      // real feature dim
#define KP   96      // padded K: 3 MFMA k-steps of 32
#define IMH  320
#define IMW  320
#define NTW  10
#define NTILE 100

// ws layout offsets unchanged from proven R3..R11
#define F_UNITS_PER_TILE 12288           // 64 rt * 3 ks * 4 c * 16 rows
#define FHI_BYTES (NTILE * F_UNITS_PER_TILE * 16)   // 19,660,800
#define SQ_OFF    (2 * FHI_BYTES)                   // 39,321,600

#define K2LOG2E 2.0813689810056077f      // (log2 e)^2: exp(-sqrt(x)) = exp2(-sqrt(K2*x))

typedef __attribute__((ext_vector_type(8))) short bf16x8;   // MFMA A/B frag
typedef __attribute__((ext_vector_type(8))) unsigned short u16x8;
typedef __attribute__((ext_vector_type(4))) float f32x4;    // MFMA C/D
typedef __attribute__((ext_vector_type(4))) __fp16 f16x4;   // 16x16x16 f16 A/B frag
typedef __attribute__((ext_vector_type(2))) __fp16 f16x2;

// ---------------- kernel A: feature build (RNE bf16) + sqf ----------------
// R20: exact revert to the R4 configuration (best measured: 111.06 us).
// R19's C-init algebra measured -2.5us WORSE: the init adds sit BEFORE the
// Gram MFMA chain (serial path) while R4's fmaf epilogue overlaps loads.
__global__ __launch_bounds__(256)
void nlm_feat_kernel(const float* __restrict__ img,
                     u16x8* __restrict__ Fhi, float* __restrict__ Sq)
{
    __shared__ float Ploc[3][6][36];   // padded rows [2p, 2p+6) of the tile
    __shared__ int   ofsl[KP];
    const int tid  = threadIdx.x;
    const int part = blockIdx.x;    // 0..15
    const int tile = blockIdx.y;
    const int by   = (tile / NTW) * TS;
    const int bx   = (tile % NTW) * TS;
    const float* Pf = &Ploc[0][0][0];

    for (int idx = tid; idx < 3 * 6 * 36; idx += 256) {
        int c   = idx / 216;
        int rem = idx - c * 216;
        int yl  = rem / 36;
        int x   = rem - yl * 36;
        int y   = 2 * part + yl;
        int iy  = min(max(y - 2, 0), TS - 1);
        int ix  = min(max(x - 2, 0), TS - 1);
        Ploc[c][yl][x] = img[(c * IMH + by + iy) * IMW + bx + ix];
    }
    if (tid < KP) {
        int k = tid, v = 0;
        if (k < DF) {
            int c = k / 24, o = k - c * 24;
            int kk = o + (o >= 12);
            int i = kk / 5, j = kk - (kk / 5) * 5;
            v = c * 216 + i * 36 + j;
        }
        ofsl[k] = v;
    }
    __syncthreads();

    if (tid < 64) {
        int m  = part * 64 + tid;
        int my = m >> 5, mx = m & 31;
        int ly0 = my - 2 * part;
        float s = 0.f;
        #pragma unroll
        for (int k = 0; k < 25; ++k) {
            if (k == 12) continue;
            int i = k / 5, j = k - (k / 5) * 5;
            float v0 = Ploc[0][ly0 + i][mx + j];
            float v1 = Ploc[1][ly0 + i][mx + j];
            float v2 = Ploc[2][ly0 + i][mx + j];
            s = fmaf(v0, v0, s); s = fmaf(v1, v1, s); s = fmaf(v2, v2, s);
        }
        Sq[tile * NPIX + m] = s * K2LOG2E;   // pre-scaled
    }

    #pragma unroll
    for (int q = 0; q < 3; ++q) {
        int u    = part * 768 + q * 256 + tid;
        int row  = u & 15;
        int c4   = (u >> 4) & 3;
        int rks  = u >> 6;
        int ks   = rks - (rks / 3) * 3;
        int rt   = rks / 3;
        int r    = rt * 16 + row;
        int lbase = ((r >> 5) - 2 * part) * 36 + (r & 31);
        u16x8 h;
        #pragma unroll
        for (int j = 0; j < 8; ++j) {
            int k = ks * 32 + c4 * 8 + j;
            unsigned short hs = 0;
            if (k < DF) {
                float f = Pf[lbase + ofsl[k]];
                unsigned int uu = __float_as_uint(f);
                hs = (unsigned short)((uu + 0x7fffu + ((uu >> 16) & 1u)) >> 16);
            }
            h[j] = hs;
        }
        Fhi[tile * F_UNITS_PER_TILE + u] = h;
    }
}

// ---------------- kernel B: Gram MFMA + PV-MFMA accumulation --------------
// R12: operand-swapped Gram (row=m,col=n); densities feed K=16 f16 PV MFMA
//      with B=[y0,y1,y2,1] (hi + lo residual) in A-fragment layout.
// R13: XCD-swizzled 1-D grid (FETCH 84->10.8MB).
// R14: 2-deep register pipeline (gemm ~61 -> <50.5). Best measured config.
// Rejected by measurement: 512-thr/3-deep (+5.3), LDS exp table (+14),
// symmetric triangle (+38/+50), C-init algebra (+3.5).
__global__ __launch_bounds__(256)
__attribute__((amdgpu_waves_per_eu(4, 8)))
void nlm_gemm_kernel(const float* __restrict__ img,
                     const bf16x8* __restrict__ Fhi,
                     const float* __restrict__ SqK, float* __restrict__ out)
{
    __shared__ __fp16 Yhi[4][1032];   // pitch 1032: banks 0/4/8/12 across c
    __shared__ __fp16 Ylo[4][1032];
    __shared__ float red[4][2][16][4];  // [wave][t][row][c]

    const int tid  = threadIdx.x;
    const int lane = tid & 63;
    const int wv   = tid >> 6;
    // XCD swizzle: block i -> XCD i%8; each XCD gets a contiguous work slab.
    const int i0   = blockIdx.x;
    const int w    = (i0 & 7) * 400 + (i0 >> 3);
    const int tile = w >> 5;
    const int rtA  = (w & 31) * 2;
    const int by   = (tile / NTW) * TS;
    const int bx   = (tile % NTW) * TS;
    const int quad = lane >> 4;
    const int col  = lane & 15;
    const int ycol = col & 3;           // cols 4..15 dup; D cols 4..15 unused

    const bf16x8* FHt = Fhi + tile * F_UNITS_PER_TILE;
    const float*  Sqt = SqK + tile * NPIX;

    // stage Y = [y0,y1,y2,1] as f16 hi + f16 residual, float4-vectorized
    for (int idx = tid; idx < 1024; idx += 256) {
        int c = idx >> 8, m4 = (idx & 255) << 2;
        f32x4 v = {1.f, 1.f, 1.f, 1.f};
        if (c < 3) v = *(const f32x4*)&img[(c * IMH + by + (m4 >> 5)) * IMW + bx + (m4 & 31)];
        f16x4 h, l;
        #pragma unroll
        for (int j = 0; j < 4; ++j) {
            h[j] = (__fp16)v[j];
            l[j] = (__fp16)(v[j] - (float)h[j]);
        }
        *(f16x4*)&Yhi[c][m4] = h;
        *(f16x4*)&Ylo[c][m4] = l;
    }

    // block's n-features, pinned (B operand of the Gram MFMA)
    bf16x8 bN[2][3];
    #pragma unroll
    for (int t = 0; t < 2; ++t)
        #pragma unroll
        for (int ks = 0; ks < 3; ++ks)
            bN[t][ks] = FHt[((rtA + t) * 3 + ks) * 64 + lane];
    asm volatile(""
        : "+v"(bN[0][0]), "+v"(bN[0][1]), "+v"(bN[0][2]),
          "+v"(bN[1][0]), "+v"(bN[1][1]), "+v"(bN[1][2]));

    float snK[2];
    #pragma unroll
    for (int t = 0; t < 2; ++t)
        snK[t] = Sqt[(rtA + t) * 16 + col];

    f32x4 DpvH0 = {0.f, 0.f, 0.f, 0.f};
    f32x4 DpvL0 = {0.f, 0.f, 0.f, 0.f};
    f32x4 DpvH1 = {0.f, 0.f, 0.f, 0.f};
    f32x4 DpvL1 = {0.f, 0.f, 0.f, 0.f};

    __syncthreads();

    const int mtBase = wv * 16;

    // two-deep ping-pong pipeline: named buffer sets A/B (no runtime indexing)
    bf16x8 aFA0, aFA1, aFA2, aFB0, aFB1, aFB2;
    f32x4 sqA, sqB;
    f16x4 bhiA, bloA, bhiB, bloB;

#define LOADF(mt, a0, a1, a2, sq, bh, bl)                      \
    do {                                                       \
        int _mt = (mt);                                        \
        a0 = FHt[(_mt * 3 + 0) * 64 + lane];                   \
        a1 = FHt[(_mt * 3 + 1) * 64 + lane];                   \
        a2 = FHt[(_mt * 3 + 2) * 64 + lane];                   \
        sq = *(const f32x4*)&Sqt[_mt * 16 + quad * 4];         \
        bh = *(const f16x4*)&Yhi[ycol][_mt * 16 + quad * 4];   \
        bl = *(const f16x4*)&Ylo[ycol][_mt * 16 + quad * 4];   \
    } while (0)

#define COMPUTE(mt, a0, a1, a2, sq, bh, bl)                                          \
    do {                                                                             \
        int _mt = (mt);                                                              \
        f32x4 C0 = {0.f, 0.f, 0.f, 0.f};                                             \
        f32x4 C1 = {0.f, 0.f, 0.f, 0.f};                                             \
        C0 = __builtin_amdgcn_mfma_f32_16x16x32_bf16(a0, bN[0][0], C0, 0, 0, 0);     \
        C1 = __builtin_amdgcn_mfma_f32_16x16x32_bf16(a0, bN[1][0], C1, 0, 0, 0);     \
        C0 = __builtin_amdgcn_mfma_f32_16x16x32_bf16(a1, bN[0][1], C0, 0, 0, 0);     \
        C1 = __builtin_amdgcn_mfma_f32_16x16x32_bf16(a1, bN[1][1], C1, 0, 0, 0);     \
        C0 = __builtin_amdgcn_mfma_f32_16x16x32_bf16(a2, bN[0][2], C0, 0, 0, 0);     \
        C1 = __builtin_amdgcn_mfma_f32_16x16x32_bf16(a2, bN[1][2], C1, 0, 0, 0);     \
        _Pragma("unroll")                                                            \
        for (int t = 0; t < 2; ++t) {                                                \
            f32x4 C = t ? C1 : C0;                                                   \
            float d[4];                                                              \
            _Pragma("unroll")                                                        \
            for (int i = 0; i < 4; ++i) {                                            \
                float s2 = fmaxf(fmaf(-2.0f * K2LOG2E, C[i], sq[i] + snK[t]), 0.f);  \
                d[i] = __builtin_amdgcn_exp2f(-__builtin_amdgcn_sqrtf(s2));          \
            }                                                                        \
            if (_mt == rtA + t) {                                                    \
                _Pragma("unroll")                                                    \
                for (int i = 0; i < 4; ++i)                                          \
                    if (quad * 4 + i == col) d[i] = 0.f;                             \
            }                                                                        \
            f16x2 p0 = __builtin_amdgcn_cvt_pkrtz(d[0], d[1]);                       \
            f16x2 p1 = __builtin_amdgcn_cvt_pkrtz(d[2], d[3]);                       \
            f16x4 wp = __builtin_shufflevector(p0, p1, 0, 1, 2, 3);                  \
            if (t == 0) {                                                            \
                DpvH0 = __builtin_amdgcn_mfma_f32_16x16x16f16(wp, bh, DpvH0, 0, 0, 0); \
                DpvL0 = __builtin_amdgcn_mfma_f32_16x16x16f16(wp, bl, DpvL0, 0, 0, 0); \
            } else {                                                                 \
                DpvH1 = __builtin_amdgcn_mfma_f32_16x16x16f16(wp, bh, DpvH1, 0, 0, 0); \
                DpvL1 = __builtin_amdgcn_mfma_f32_16x16x16f16(wp, bl, DpvL1, 0, 0, 0); \
            }                                                                        \
        }                                                                            \
    } while (0)

    LOADF(mtBase, aFA0, aFA1, aFA2, sqA, bhiA, bloA);
    #pragma unroll
    for (int it2 = 0; it2 < 8; ++it2) {
        const int mt0 = mtBase + it2 * 2;
        LOADF(mt0 + 1, aFB0, aFB1, aFB2, sqB, bhiB, bloB);
        COMPUTE(mt0, aFA0, aFA1, aFA2, sqA, bhiA, bloA);
        if (it2 < 7)
            LOADF(mt0 + 2, aFA0, aFA1, aFA2, sqA, bhiA, bloA);
        COMPUTE(mt0 + 1, aFB0, aFB1, aFB2, sqB, bhiB, bloB);
    }
#undef LOADF
#undef COMPUTE

    // cross-wave reduce: Dpv row = n-local (4q+i), col = channel (0..3 valid)
    if (col < 4) {
        #pragma unroll
        for (int i = 0; i < 4; ++i) {
            red[wv][0][quad * 4 + i][col] = DpvH0[i] + DpvL0[i];
            red[wv][1][quad * 4 + i][col] = DpvH1[i] + DpvL1[i];
        }
    }
    __syncthreads();

    if (tid < 128) {
        int n = tid >> 2, c = tid & 3;
        int t = n >> 4, r = n & 15;
        float s = red[0][t][r][c] + red[1][t][r][c]
                + red[2][t][r][c] + red[3][t][r][c];
        float rs = __shfl(s, (tid & 63) | 3, 64);   // c==3 slot = rowsum
        if (c < 3) {
            int nn = rtA * 16 + n;
            int gy = by + (nn >> 5), gx = bx + (nn & 31);
            out[(c * IMH + gy) * IMW + gx] = s * (1.0f / rs);
        }
    }
}

extern "C" void kernel_launch(void* const* d_in, const int* in_sizes, int n_in,
                              void* d_out, int out_size, void* d_ws, size_t ws_size,
                              hipStream_t stream) {
    const float* img = (const float*)d_in[0];
    float* out = (float*)d_out;
    char* ws = (char*)d_ws;
    u16x8* Fhi = (u16x8*)ws;
    float* Sq  = (float*)(ws + SQ_OFF);

    dim3 fgrid(16, NTILE);
    nlm_feat_kernel<<<fgrid, 256, 0, stream>>>(img, Fhi, Sq);
    nlm_gemm_kernel<<<dim3(3200), 256, 0, stream>>>(img, (const bf16x8*)Fhi, Sq, out);
}